// Round 6
// baseline (93.312 us; speedup 1.0000x reference)
//
#include <hip/hip_runtime.h>
#include <hip/hip_bf16.h>
#include <math.h>

constexpr int IN_F = 128, OUT_F = 256, NH = 4, HD = 64;
constexpr int B = 8, N = 1024;
#define NEG 0.2f

typedef __attribute__((ext_vector_type(8))) short bf16x8;
typedef __attribute__((ext_vector_type(4))) float f32x4;
typedef __attribute__((ext_vector_type(8))) unsigned short u16x8;

static __device__ __forceinline__ short f2bf(float f) {
    __hip_bfloat16 b = __float2bfloat16(f);
    return *reinterpret_cast<short*>(&b);
}

// ---------------- Kernel 0: bit-pack adjacency, pre-transposed per 64-row tile ----------------
// pkdT layout: [B][16 tiles][32 words][64 rows] u32; word w2 = j/32, row = n&63.
// grid = B*N blocks, 256 threads. Wave wv covers j in [256wv, 256wv+256).
__global__ __launch_bounds__(256) void k_pack(
    const int* __restrict__ adj,          // [B*N, N]
    unsigned* __restrict__ pkdT)
{
    const int row = blockIdx.x;           // b*N + n
    const int b = row >> 10, n = row & (N - 1);
    const int t = threadIdx.x, lane = t & 63, wv = t >> 6;
    const int* __restrict__ a = adj + (size_t)row * N + (wv << 8);
    unsigned* __restrict__ dst = pkdT + ((size_t)(b * 16 + (n >> 6))) * 32 * 64 + (n & 63);
#pragma unroll
    for (int c = 0; c < 4; ++c) {
        const int v = a[(c << 6) + lane];                 // coalesced 256B per instr
        const unsigned long long m = __ballot(v != 0);    // bit l = row's j = 256wv+64c+l
        if (lane == 0) {
            const int w2 = wv * 8 + c * 2;
            dst[(size_t)w2 * 64]       = (unsigned)m;
            dst[(size_t)(w2 + 1) * 64] = (unsigned)(m >> 32);
        }
    }
}

// ---------------- Kernel 1: h = x @ W  ->  hT (bf16, [B][H][64][N]) + scores ----------------
__global__ __launch_bounds__(256) void k_gemm(
    const float* __restrict__ x,          // [B*N, 128]
    const float* __restrict__ W,          // [128, 256]
    const float* __restrict__ a,          // [128]
    unsigned short* __restrict__ hT,      // [B][H][64][N] bf16 bits (transposed)
    float* __restrict__ siT,              // [B][H][N]
    float* __restrict__ sjT)              // [B][H][N]
{
    constexpr int ROWS = 8;
    __shared__ float xs[ROWS][IN_F];   // 4 KB
    const int t = threadIdx.x;
    const int row0 = blockIdx.x * ROWS;

    ((float4*)xs)[t] = ((const float4*)(x + (size_t)row0 * IN_F))[t];
    __syncthreads();

    float acc[ROWS];
#pragma unroll
    for (int r = 0; r < ROWS; ++r) acc[r] = 0.f;

    for (int k0 = 0; k0 < IN_F; k0 += 4) {
        float4 xr[ROWS];
#pragma unroll
        for (int r = 0; r < ROWS; ++r) xr[r] = *(const float4*)&xs[r][k0];
#pragma unroll
        for (int kk = 0; kk < 4; ++kk) {
            const float w = W[(k0 + kk) * OUT_F + t];   // coalesced, L2-hot
#pragma unroll
            for (int r = 0; r < ROWS; ++r)
                acc[r] = fmaf(((const float*)&xr[r])[kk], w, acc[r]);
        }
    }

    const int lane = t & 63, head = t >> 6, d = t & 63;
    const int b = row0 >> 10, n0 = row0 & (N - 1);

    u16x8 pk;
#pragma unroll
    for (int r = 0; r < ROWS; ++r) pk[r] = (unsigned short)f2bf(acc[r]);
    *(u16x8*)&hT[((size_t)(b * NH + head) * HD + d) * N + n0] = pk;

    const float ai = a[lane], aj = a[HD + lane];
#pragma unroll
    for (int r = 0; r < ROWS; ++r) {
        float si = acc[r] * ai;
        float sj = acc[r] * aj;
#pragma unroll
        for (int off = 32; off; off >>= 1) {
            si += __shfl_xor(si, off, 64);
            sj += __shfl_xor(sj, off, 64);
        }
        if (lane == 0) {
            siT[(size_t)(b * NH + head) * N + n0 + r] = si;
            sjT[(size_t)(b * NH + head) * N + n0 + r] = sj;
        }
    }
}

// ---------------- Kernel 2: MFMA PV, 8 waves: j-range split 2-way, LDS combine ----------------
// grid = B * H * (N/64) = 512 blocks, 512 threads (8 waves).
// Wave w: i-rows [i0 + (w&3)*16, +16), j in [(w>>2)*512, +512). 16 waves/CU.
__global__ __launch_bounds__(512, 4) void k_pv(
    const unsigned short* __restrict__ hT,   // [B][H][64][N] bf16
    const float* __restrict__ siT,           // [B][H][N]
    const float* __restrict__ sjT,           // [B][H][N]
    const unsigned* __restrict__ pkdT,       // [B][16][32][64] packed bits
    float* __restrict__ out)                 // [B][N][256]
{
    constexpr int TJ = 64, NIT = 512 / TJ;   // 8 iterations per wave
    __shared__ float sjs[N];                 // 4 KB
    __shared__ unsigned pwl[32 * 64];        // 8 KB: [word][local row]
    __shared__ float zbuf[8][16];            // 0.5 KB
    __shared__ float accb[4][64][17];        // 17 KB, padded: conflict-free scalar access

    const int bid = blockIdx.x;
    const int itile = bid & 15, h = (bid >> 4) & 3, b = bid >> 6;
    const int t = threadIdx.x, lane = t & 63, w = t >> 6;
    const int g = w & 3;                     // i-group
    const int jbase = (w >> 2) << 9;         // 0 or 512
    const int i0 = itile * 64 + g * 16;

    ((float2*)sjs)[t] = ((const float2*)(sjT + (size_t)(b * NH + h) * N))[t];
    ((uint4*)pwl)[t] = ((const uint4*)(pkdT + ((size_t)(b * 16 + itile)) * 32 * 64))[t];

    const int il = lane & 15, q = lane >> 4, qc = q * 8;
    const int lr = g * 16 + il;
    const int i = i0 + il;
    const float si = siT[(size_t)(b * NH + h) * N + i];
    const unsigned short* __restrict__ hrow =
        hT + (size_t)(b * NH + h) * HD * N + (size_t)il * N + qc + jbase;

    f32x4 acc0 = {0.f,0.f,0.f,0.f}, acc1 = {0.f,0.f,0.f,0.f};
    f32x4 acc2 = {0.f,0.f,0.f,0.f}, acc3 = {0.f,0.f,0.f,0.f};
    float psA = 0.f, psB = 0.f;

    // prologue: prefetch iteration 0 h-frags (L2-hot)
    bf16x8 cb00 = *(const bf16x8*)(hrow + 0 * 16 * N);
    bf16x8 cb01 = *(const bf16x8*)(hrow + 1 * 16 * N);
    bf16x8 cb02 = *(const bf16x8*)(hrow + 2 * 16 * N);
    bf16x8 cb03 = *(const bf16x8*)(hrow + 3 * 16 * N);
    bf16x8 cb10 = *(const bf16x8*)(hrow + 0 * 16 * N + 32);
    bf16x8 cb11 = *(const bf16x8*)(hrow + 1 * 16 * N + 32);
    bf16x8 cb12 = *(const bf16x8*)(hrow + 2 * 16 * N + 32);
    bf16x8 cb13 = *(const bf16x8*)(hrow + 3 * 16 * N + 32);

    __syncthreads();   // sjs + pwl visible

    for (int itr = 0; itr < NIT; ++itr) {
        const int jloc = itr * TJ;
        const int jn = (jloc + TJ) & 511;    // wrap within this wave's half: valid, branch-free

        const bf16x8 nb00 = *(const bf16x8*)(hrow + 0 * 16 * N + jn);
        const bf16x8 nb01 = *(const bf16x8*)(hrow + 1 * 16 * N + jn);
        const bf16x8 nb02 = *(const bf16x8*)(hrow + 2 * 16 * N + jn);
        const bf16x8 nb03 = *(const bf16x8*)(hrow + 3 * 16 * N + jn);
        const bf16x8 nb10 = *(const bf16x8*)(hrow + 0 * 16 * N + jn + 32);
        const bf16x8 nb11 = *(const bf16x8*)(hrow + 1 * 16 * N + jn + 32);
        const bf16x8 nb12 = *(const bf16x8*)(hrow + 2 * 16 * N + jn + 32);
        const bf16x8 nb13 = *(const bf16x8*)(hrow + 3 * 16 * N + jn + 32);

        const int jg = jbase + jloc;
        const int w2 = jg >> 5;

        // ---- k-step 0: j = jg + qc + e
        {
            const unsigned byte = (pwl[(w2 + 0) * 64 + lr] >> qc) & 0xffu;
            const int jq = jg + qc;
            const float4 s0 = *(const float4*)&sjs[jq];
            const float4 s1 = *(const float4*)&sjs[jq + 4];
            const float sv[8] = {s0.x,s0.y,s0.z,s0.w,s1.x,s1.y,s1.z,s1.w};
            bf16x8 af;
#pragma unroll
            for (int e = 0; e < 8; ++e) {
                float ev = si + sv[e];
                ev = (ev >= 0.f) ? ev : NEG * ev;
                const float pe = ((byte >> e) & 1u) ? __expf(ev) : 0.f;
                psA += pe;
                af[e] = f2bf(pe);
            }
            acc0 = __builtin_amdgcn_mfma_f32_16x16x32_bf16(af, cb00, acc0, 0, 0, 0);
            acc1 = __builtin_amdgcn_mfma_f32_16x16x32_bf16(af, cb01, acc1, 0, 0, 0);
            acc2 = __builtin_amdgcn_mfma_f32_16x16x32_bf16(af, cb02, acc2, 0, 0, 0);
            acc3 = __builtin_amdgcn_mfma_f32_16x16x32_bf16(af, cb03, acc3, 0, 0, 0);
        }
        // ---- k-step 1: j = jg + 32 + qc + e
        {
            const unsigned byte = (pwl[(w2 + 1) * 64 + lr] >> qc) & 0xffu;
            const int jq = jg + 32 + qc;
            const float4 s0 = *(const float4*)&sjs[jq];
            const float4 s1 = *(const float4*)&sjs[jq + 4];
            const float sv[8] = {s0.x,s0.y,s0.z,s0.w,s1.x,s1.y,s1.z,s1.w};
            bf16x8 af;
#pragma unroll
            for (int e = 0; e < 8; ++e) {
                float ev = si + sv[e];
                ev = (ev >= 0.f) ? ev : NEG * ev;
                const float pe = ((byte >> e) & 1u) ? __expf(ev) : 0.f;
                psB += pe;
                af[e] = f2bf(pe);
            }
            acc0 = __builtin_amdgcn_mfma_f32_16x16x32_bf16(af, cb10, acc0, 0, 0, 0);
            acc1 = __builtin_amdgcn_mfma_f32_16x16x32_bf16(af, cb11, acc1, 0, 0, 0);
            acc2 = __builtin_amdgcn_mfma_f32_16x16x32_bf16(af, cb12, acc2, 0, 0, 0);
            acc3 = __builtin_amdgcn_mfma_f32_16x16x32_bf16(af, cb13, acc3, 0, 0, 0);
        }

        cb00 = nb00; cb01 = nb01; cb02 = nb02; cb03 = nb03;
        cb10 = nb10; cb11 = nb11; cb12 = nb12; cb13 = nb13;
    }

    // ---- Z partial: reduce over the 4 k-quarter lanes
    float ps = psA + psB;
    ps += __shfl_xor(ps, 16, 64);
    ps += __shfl_xor(ps, 32, 64);
    if (lane < 16) zbuf[w][lane] = ps;

    // ---- waves 4-7 dump accumulators to LDS
    if (w >= 4) {
        float* p = &accb[g][lane][0];
#pragma unroll
        for (int r = 0; r < 4; ++r) {
            p[r]      = acc0[r];
            p[4 + r]  = acc1[r];
            p[8 + r]  = acc2[r];
            p[12 + r] = acc3[r];
        }
    }
    __syncthreads();

    // ---- waves 0-3 combine + normalize + write
    if (w < 4) {
        const float* p = &accb[w][lane][0];
#pragma unroll
        for (int r = 0; r < 4; ++r) {
            acc0[r] += p[r];
            acc1[r] += p[4 + r];
            acc2[r] += p[8 + r];
            acc3[r] += p[12 + r];
        }
        float iz[4];
#pragma unroll
        for (int r = 0; r < 4; ++r)
            iz[r] = 1.f / (zbuf[w][q * 4 + r] + zbuf[w + 4][q * 4 + r]);

        float* __restrict__ ob = out + ((size_t)b * N + itile * 64 + w * 16) * OUT_F + h * HD + il;
#pragma unroll
        for (int r = 0; r < 4; ++r) {
            float* o = ob + (size_t)(q * 4 + r) * OUT_F;
            o[0]  = acc0[r] * iz[r];
            o[16] = acc1[r] * iz[r];
            o[32] = acc2[r] * iz[r];
            o[48] = acc3[r] * iz[r];
        }
    }
}

extern "C" void kernel_launch(void* const* d_in, const int* in_sizes, int n_in,
                              void* d_out, int out_size, void* d_ws, size_t ws_size,
                              hipStream_t stream) {
    const float* x   = (const float*)d_in[0];
    const int*   adj = (const int*)d_in[1];
    const float* W   = (const float*)d_in[2];
    const float* a   = (const float*)d_in[3];
    float* out = (float*)d_out;

    unsigned short* hT = (unsigned short*)d_ws;                        // 4 MB bf16
    float* siT = (float*)(hT + (size_t)B * NH * HD * N);               // 128 KB
    float* sjT = siT + (size_t)B * NH * N;                             // 128 KB
    unsigned* pkdT = (unsigned*)(sjT + (size_t)B * NH * N);            // 1 MB

    k_pack<<<B * N, 256, 0, stream>>>(adj, pkdT);
    k_gemm<<<B * N / 8, 256, 0, stream>>>(x, W, a, hT, siT, sjT);
    k_pv<<<B * NH * (N / 64), 512, 0, stream>>>(hT, siT, sjT, pkdT, out);
}

// Round 7
// 66.826 us; speedup vs baseline: 1.3963x; 1.3963x over previous
//
#include <hip/hip_runtime.h>
#include <hip/hip_bf16.h>
#include <math.h>

constexpr int IN_F = 128, OUT_F = 256, NH = 4, HD = 64;
constexpr int B = 8, N = 1024;
#define NEG 0.2f

typedef __attribute__((ext_vector_type(8))) short bf16x8;
typedef __attribute__((ext_vector_type(4))) float f32x4;
typedef __attribute__((ext_vector_type(8))) unsigned short u16x8;

static __device__ __forceinline__ short f2bf(float f) {
    __hip_bfloat16 b = __float2bfloat16(f);
    return *reinterpret_cast<short*>(&b);
}

// ---------------- Kernel 0: bit-pack adjacency, pre-transposed per 64-row tile ----------------
// pkdT layout: [B][16 tiles][32 words][64 rows] u32; word w2 = j/32, row = n&63.
__global__ __launch_bounds__(256) void k_pack(
    const int* __restrict__ adj,          // [B*N, N]
    unsigned* __restrict__ pkdT)
{
    const int row = blockIdx.x;           // b*N + n
    const int b = row >> 10, n = row & (N - 1);
    const int t = threadIdx.x, lane = t & 63, wv = t >> 6;
    const int* __restrict__ a = adj + (size_t)row * N + (wv << 8);
    unsigned* __restrict__ dst = pkdT + ((size_t)(b * 16 + (n >> 6))) * 32 * 64 + (n & 63);
#pragma unroll
    for (int c = 0; c < 4; ++c) {
        const int v = a[(c << 6) + lane];                 // coalesced 256B per instr
        const unsigned long long m = __ballot(v != 0);    // bit l -> j = 256wv+64c+l
        if (lane == 0) {
            const int w2 = wv * 8 + c * 2;
            dst[(size_t)w2 * 64]       = (unsigned)m;
            dst[(size_t)(w2 + 1) * 64] = (unsigned)(m >> 32);
        }
    }
}

// ---------------- Kernel 1: h = x @ W  ->  hT (bf16, [B][H][64][N]) + scores ----------------
__global__ __launch_bounds__(256) void k_gemm(
    const float* __restrict__ x,          // [B*N, 128]
    const float* __restrict__ W,          // [128, 256]
    const float* __restrict__ a,          // [128]
    unsigned short* __restrict__ hT,      // [B][H][64][N] bf16 bits (transposed)
    float* __restrict__ siT,              // [B][H][N]
    float* __restrict__ sjT)              // [B][H][N]
{
    constexpr int ROWS = 8;
    __shared__ float xs[ROWS][IN_F];   // 4 KB
    const int t = threadIdx.x;
    const int row0 = blockIdx.x * ROWS;

    ((float4*)xs)[t] = ((const float4*)(x + (size_t)row0 * IN_F))[t];
    __syncthreads();

    float acc[ROWS];
#pragma unroll
    for (int r = 0; r < ROWS; ++r) acc[r] = 0.f;

    for (int k0 = 0; k0 < IN_F; k0 += 4) {
        float4 xr[ROWS];
#pragma unroll
        for (int r = 0; r < ROWS; ++r) xr[r] = *(const float4*)&xs[r][k0];
#pragma unroll
        for (int kk = 0; kk < 4; ++kk) {
            const float w = W[(k0 + kk) * OUT_F + t];   // coalesced, L2-hot
#pragma unroll
            for (int r = 0; r < ROWS; ++r)
                acc[r] = fmaf(((const float*)&xr[r])[kk], w, acc[r]);
        }
    }

    const int lane = t & 63, head = t >> 6, d = t & 63;
    const int b = row0 >> 10, n0 = row0 & (N - 1);

    u16x8 pk;
#pragma unroll
    for (int r = 0; r < ROWS; ++r) pk[r] = (unsigned short)f2bf(acc[r]);
    *(u16x8*)&hT[((size_t)(b * NH + head) * HD + d) * N + n0] = pk;

    const float ai = a[lane], aj = a[HD + lane];
#pragma unroll
    for (int r = 0; r < ROWS; ++r) {
        float si = acc[r] * ai;
        float sj = acc[r] * aj;
#pragma unroll
        for (int off = 32; off; off >>= 1) {
            si += __shfl_xor(si, off, 64);
            sj += __shfl_xor(sj, off, 64);
        }
        if (lane == 0) {
            siT[(size_t)(b * NH + head) * N + n0 + r] = si;
            sjT[(size_t)(b * NH + head) * N + n0 + r] = sj;
        }
    }
}

// ---------------- Kernel 2: MFMA PV; 1024 blocks x 4 waves; (g i-subtile) x (jh j-half) ----------------
// grid = B * H * (N/32) = 1024 blocks, 256 threads. Wave w: g=w&1 (16 i-rows), jh=w>>1 (512 j's).
// 4 blocks/CU (launch_bounds cap 128 VGPR), 16 waves/CU. In-block LDS combine of the two j-halves.
__global__ __launch_bounds__(256, 4) void k_pv(
    const unsigned short* __restrict__ hT,   // [B][H][64][N] bf16
    const float* __restrict__ siT,           // [B][H][N]
    const float* __restrict__ sjT,           // [B][H][N]
    const unsigned* __restrict__ pkdT,       // [B][16][32][64] packed bits
    float* __restrict__ out)                 // [B][N][256]
{
    constexpr int TJ = 64, NIT = 512 / TJ;   // 8 iterations per wave
    __shared__ float sjs[N];                 // 4 KB
    __shared__ unsigned pwl[32 * 32];        // 4 KB: [word w2][local row 0..31]
    __shared__ float zbuf[4][16];            // 256 B
    __shared__ float accb[2][64][17];        // 8.5 KB padded

    const int bid = blockIdx.x;
    const int it32 = bid & 31, h = (bid >> 5) & 3, b = bid >> 7;
    const int t = threadIdx.x, lane = t & 63, w = t >> 6;
    const int g = w & 1;                     // i-subtile (16 rows)
    const int jbase = (w >> 1) << 9;         // 0 or 512
    const int i0 = it32 * 32;

    ((float4*)sjs)[t] = ((const float4*)(sjT + (size_t)(b * NH + h) * N))[t];

    // stage packed bits for rows i0..i0+31: src [32 w2][64 rows], take row-offset (i0&32)
    {
        const unsigned* src = pkdT + ((size_t)(b * 16 + (i0 >> 6))) * 32 * 64 + (i0 & 32);
        const int w2 = t >> 3, r4 = (t & 7) * 4;
        *(uint4*)&pwl[w2 * 32 + r4] = *(const uint4*)&src[(size_t)w2 * 64 + r4];
    }

    const int il = lane & 15, q = lane >> 4, qc = q * 8;
    const int lr = g * 16 + il;              // local row in pwl
    const int i = i0 + g * 16 + il;
    const float si = siT[(size_t)(b * NH + h) * N + i];
    const unsigned short* __restrict__ hrow =
        hT + (size_t)(b * NH + h) * HD * N + (size_t)il * N + qc + jbase;

    f32x4 acc0 = {0.f,0.f,0.f,0.f}, acc1 = {0.f,0.f,0.f,0.f};
    f32x4 acc2 = {0.f,0.f,0.f,0.f}, acc3 = {0.f,0.f,0.f,0.f};
    float psA = 0.f, psB = 0.f;

    // prologue: prefetch iteration 0 h-frags (L2-hot)
    bf16x8 cb00 = *(const bf16x8*)(hrow + 0 * 16 * N);
    bf16x8 cb01 = *(const bf16x8*)(hrow + 1 * 16 * N);
    bf16x8 cb02 = *(const bf16x8*)(hrow + 2 * 16 * N);
    bf16x8 cb03 = *(const bf16x8*)(hrow + 3 * 16 * N);
    bf16x8 cb10 = *(const bf16x8*)(hrow + 0 * 16 * N + 32);
    bf16x8 cb11 = *(const bf16x8*)(hrow + 1 * 16 * N + 32);
    bf16x8 cb12 = *(const bf16x8*)(hrow + 2 * 16 * N + 32);
    bf16x8 cb13 = *(const bf16x8*)(hrow + 3 * 16 * N + 32);

    __syncthreads();   // sjs + pwl visible

    for (int itr = 0; itr < NIT; ++itr) {
        const int jloc = itr * TJ;
        const int jn = (jloc + TJ) & 511;    // wrap within this wave's half

        const bf16x8 nb00 = *(const bf16x8*)(hrow + 0 * 16 * N + jn);
        const bf16x8 nb01 = *(const bf16x8*)(hrow + 1 * 16 * N + jn);
        const bf16x8 nb02 = *(const bf16x8*)(hrow + 2 * 16 * N + jn);
        const bf16x8 nb03 = *(const bf16x8*)(hrow + 3 * 16 * N + jn);
        const bf16x8 nb10 = *(const bf16x8*)(hrow + 0 * 16 * N + jn + 32);
        const bf16x8 nb11 = *(const bf16x8*)(hrow + 1 * 16 * N + jn + 32);
        const bf16x8 nb12 = *(const bf16x8*)(hrow + 2 * 16 * N + jn + 32);
        const bf16x8 nb13 = *(const bf16x8*)(hrow + 3 * 16 * N + jn + 32);

        const int jg = jbase + jloc;
        const int w2 = jg >> 5;

        // ---- k-step 0: j = jg + qc + e
        {
            const unsigned byte = (pwl[(w2 + 0) * 32 + lr] >> qc) & 0xffu;
            const float4 s0 = *(const float4*)&sjs[jg + qc];
            const float4 s1 = *(const float4*)&sjs[jg + qc + 4];
            const float sv[8] = {s0.x,s0.y,s0.z,s0.w,s1.x,s1.y,s1.z,s1.w};
            bf16x8 af;
#pragma unroll
            for (int e = 0; e < 8; ++e) {
                const float ev0 = si + sv[e];
                const float ev = fmaxf(ev0, NEG * ev0);          // LeakyReLU, 2 ops
                const float pe = ((byte >> e) & 1u) ? __expf(ev) : 0.f;
                psA += pe;
                af[e] = f2bf(pe);
            }
            acc0 = __builtin_amdgcn_mfma_f32_16x16x32_bf16(af, cb00, acc0, 0, 0, 0);
            acc1 = __builtin_amdgcn_mfma_f32_16x16x32_bf16(af, cb01, acc1, 0, 0, 0);
            acc2 = __builtin_amdgcn_mfma_f32_16x16x32_bf16(af, cb02, acc2, 0, 0, 0);
            acc3 = __builtin_amdgcn_mfma_f32_16x16x32_bf16(af, cb03, acc3, 0, 0, 0);
        }
        // ---- k-step 1: j = jg + 32 + qc + e
        {
            const unsigned byte = (pwl[(w2 + 1) * 32 + lr] >> qc) & 0xffu;
            const float4 s0 = *(const float4*)&sjs[jg + 32 + qc];
            const float4 s1 = *(const float4*)&sjs[jg + 32 + qc + 4];
            const float sv[8] = {s0.x,s0.y,s0.z,s0.w,s1.x,s1.y,s1.z,s1.w};
            bf16x8 af;
#pragma unroll
            for (int e = 0; e < 8; ++e) {
                const float ev0 = si + sv[e];
                const float ev = fmaxf(ev0, NEG * ev0);
                const float pe = ((byte >> e) & 1u) ? __expf(ev) : 0.f;
                psB += pe;
                af[e] = f2bf(pe);
            }
            acc0 = __builtin_amdgcn_mfma_f32_16x16x32_bf16(af, cb10, acc0, 0, 0, 0);
            acc1 = __builtin_amdgcn_mfma_f32_16x16x32_bf16(af, cb11, acc1, 0, 0, 0);
            acc2 = __builtin_amdgcn_mfma_f32_16x16x32_bf16(af, cb12, acc2, 0, 0, 0);
            acc3 = __builtin_amdgcn_mfma_f32_16x16x32_bf16(af, cb13, acc3, 0, 0, 0);
        }

        cb00 = nb00; cb01 = nb01; cb02 = nb02; cb03 = nb03;
        cb10 = nb10; cb11 = nb11; cb12 = nb12; cb13 = nb13;
    }

    // ---- Z partial: reduce over the 4 k-quarter lanes
    float ps = psA + psB;
    ps += __shfl_xor(ps, 16, 64);
    ps += __shfl_xor(ps, 32, 64);
    if (lane < 16) zbuf[w][lane] = ps;

    // ---- jh=1 waves dump accumulators to LDS
    if (w >= 2) {
        float* p = &accb[g][lane][0];
#pragma unroll
        for (int r = 0; r < 4; ++r) {
            p[r]      = acc0[r];
            p[4 + r]  = acc1[r];
            p[8 + r]  = acc2[r];
            p[12 + r] = acc3[r];
        }
    }
    __syncthreads();

    // ---- jh=0 waves combine + normalize + write
    if (w < 2) {
        const float* p = &accb[w][lane][0];
#pragma unroll
        for (int r = 0; r < 4; ++r) {
            acc0[r] += p[r];
            acc1[r] += p[4 + r];
            acc2[r] += p[8 + r];
            acc3[r] += p[12 + r];
        }
        float iz[4];
#pragma unroll
        for (int r = 0; r < 4; ++r)
            iz[r] = 1.f / (zbuf[w][q * 4 + r] + zbuf[w + 2][q * 4 + r]);

        float* __restrict__ ob = out + ((size_t)b * N + i0 + w * 16) * OUT_F + h * HD + il;
#pragma unroll
        for (int r = 0; r < 4; ++r) {
            float* o = ob + (size_t)(q * 4 + r) * OUT_F;
            o[0]  = acc0[r] * iz[r];
            o[16] = acc1[r] * iz[r];
            o[32] = acc2[r] * iz[r];
            o[48] = acc3[r] * iz[r];
        }
    }
}

extern "C" void kernel_launch(void* const* d_in, const int* in_sizes, int n_in,
                              void* d_out, int out_size, void* d_ws, size_t ws_size,
                              hipStream_t stream) {
    const float* x   = (const float*)d_in[0];
    const int*   adj = (const int*)d_in[1];
    const float* W   = (const float*)d_in[2];
    const float* a   = (const float*)d_in[3];
    float* out = (float*)d_out;

    unsigned short* hT = (unsigned short*)d_ws;                        // 4 MB bf16
    float* siT = (float*)(hT + (size_t)B * NH * HD * N);               // 128 KB
    float* sjT = siT + (size_t)B * NH * N;                             // 128 KB
    unsigned* pkdT = (unsigned*)(sjT + (size_t)B * NH * N);            // 1 MB

    k_pack<<<B * N, 256, 0, stream>>>(adj, pkdT);
    k_gemm<<<B * N / 8, 256, 0, stream>>>(x, W, a, hT, siT, sjT);
    k_pv<<<B * NH * (N / 32), 256, 0, stream>>>(hT, siT, sjT, pkdT, out);
}

// Round 8
// 63.780 us; speedup vs baseline: 1.4630x; 1.0478x over previous
//
#include <hip/hip_runtime.h>
#include <hip/hip_bf16.h>
#include <math.h>

constexpr int IN_F = 128, OUT_F = 256, NH = 4, HD = 64;
constexpr int B = 8, N = 1024;
#define NEG 0.2f

typedef __attribute__((ext_vector_type(8))) short bf16x8;
typedef __attribute__((ext_vector_type(4))) float f32x4;
typedef __attribute__((ext_vector_type(8))) unsigned short u16x8;

static __device__ __forceinline__ short f2bf(float f) {
    __hip_bfloat16 b = __float2bfloat16(f);
    return *reinterpret_cast<short*>(&b);
}

// ---------------- Kernel 0: bit-pack adjacency, pre-transposed per 64-row tile ----------------
// pkdT layout: [B][16 tiles][32 words][64 rows] u32; word w2 = j/32, row = n&63.
__global__ __launch_bounds__(256) void k_pack(
    const int* __restrict__ adj,          // [B*N, N]
    unsigned* __restrict__ pkdT)
{
    const int row = blockIdx.x;           // b*N + n
    const int b = row >> 10, n = row & (N - 1);
    const int t = threadIdx.x, lane = t & 63, wv = t >> 6;
    const int* __restrict__ a = adj + (size_t)row * N + (wv << 8);
    unsigned* __restrict__ dst = pkdT + ((size_t)(b * 16 + (n >> 6))) * 32 * 64 + (n & 63);
#pragma unroll
    for (int c = 0; c < 4; ++c) {
        const int v = a[(c << 6) + lane];                 // coalesced 256B per instr
        const unsigned long long m = __ballot(v != 0);    // bit l -> j = 256wv+64c+l
        if (lane == 0) {
            const int w2 = wv * 8 + c * 2;
            dst[(size_t)w2 * 64]       = (unsigned)m;
            dst[(size_t)(w2 + 1) * 64] = (unsigned)(m >> 32);
        }
    }
}

// ---------------- Kernel 1: h = x @ W (round-2 proven version) ----------------
__global__ __launch_bounds__(256) void k_gemm(
    const float* __restrict__ x,          // [B*N, 128]
    const float* __restrict__ W,          // [128, 256]
    const float* __restrict__ a,          // [128]
    unsigned short* __restrict__ hT,      // [B][H][64][N] bf16 bits (transposed)
    float* __restrict__ siT,              // [B][H][N]
    float* __restrict__ sjT)              // [B][H][N]
{
    constexpr int ROWS = 8;
    __shared__ float xs[ROWS][IN_F];   // 4 KB
    const int t = threadIdx.x;
    const int row0 = blockIdx.x * ROWS;

    ((float4*)xs)[t] = ((const float4*)(x + (size_t)row0 * IN_F))[t];
    __syncthreads();

    float acc[ROWS];
#pragma unroll
    for (int r = 0; r < ROWS; ++r) acc[r] = 0.f;
    for (int k = 0; k < IN_F; ++k) {
        const float w = W[k * OUT_F + t];   // coalesced across t
#pragma unroll
        for (int r = 0; r < ROWS; ++r) acc[r] = fmaf(xs[r][k], w, acc[r]);
    }

    const int lane = t & 63, head = t >> 6, d = t & 63;
    const int b = row0 >> 10, n0 = row0 & (N - 1);

    u16x8 pk;
#pragma unroll
    for (int r = 0; r < ROWS; ++r) pk[r] = (unsigned short)f2bf(acc[r]);
    *(u16x8*)&hT[((size_t)(b * NH + head) * HD + d) * N + n0] = pk;

    const float ai = a[lane], aj = a[HD + lane];
#pragma unroll
    for (int r = 0; r < ROWS; ++r) {
        float si = acc[r] * ai;
        float sj = acc[r] * aj;
#pragma unroll
        for (int off = 32; off; off >>= 1) {
            si += __shfl_xor(si, off, 64);
            sj += __shfl_xor(sj, off, 64);
        }
        if (lane == 0) {
            siT[(size_t)(b * NH + head) * N + n0 + r] = si;
            sjT[(size_t)(b * NH + head) * N + n0 + r] = sj;
        }
    }
}

// ---------------- Kernel 2: MFMA PV; TJ=32, depth-3 register pipeline, no loop barriers ----------------
// grid = B * H * (N/32) = 1024 blocks, 256 threads. Wave w: g=w&1 (16 i-rows), jh=w>>1 (512 j's).
__global__ __launch_bounds__(256, 3) void k_pv(
    const unsigned short* __restrict__ hT,   // [B][H][64][N] bf16
    const float* __restrict__ siT,           // [B][H][N]
    const float* __restrict__ sjT,           // [B][H][N]
    const unsigned* __restrict__ pkdT,       // [B][16][32][64] packed bits
    float* __restrict__ out)                 // [B][N][256]
{
    __shared__ float sjs[N];                 // 4 KB
    __shared__ unsigned pwl[32 * 32];        // 4 KB: [word w2][local row 0..31]
    __shared__ float zbuf[4][16];            // 256 B
    __shared__ float accb[2][64][17];        // 8.5 KB padded

    const int bid = blockIdx.x;
    const int it32 = bid & 31, h = (bid >> 5) & 3, b = bid >> 7;
    const int t = threadIdx.x, lane = t & 63, w = t >> 6;
    const int g = w & 1;                     // i-subtile (16 rows)
    const int jbase = (w >> 1) << 9;         // 0 or 512
    const int i0 = it32 * 32;

    ((float4*)sjs)[t] = ((const float4*)(sjT + (size_t)(b * NH + h) * N))[t];
    {   // stage packed bits for rows i0..i0+31
        const unsigned* src = pkdT + ((size_t)(b * 16 + (i0 >> 6))) * 32 * 64 + (i0 & 32);
        const int w2 = t >> 3, r4 = (t & 7) * 4;
        *(uint4*)&pwl[w2 * 32 + r4] = *(const uint4*)&src[(size_t)w2 * 64 + r4];
    }

    const int il = lane & 15, q = lane >> 4, qc = q * 8;
    const int lr = g * 16 + il;              // local row in pwl
    const int i = i0 + g * 16 + il;
    const float si = siT[(size_t)(b * NH + h) * N + i];
    const unsigned short* __restrict__ hrow =
        hT + (size_t)(b * NH + h) * HD * N + (size_t)il * N + qc + jbase;

    f32x4 acc0 = {0.f,0.f,0.f,0.f}, acc1 = {0.f,0.f,0.f,0.f};
    f32x4 acc2 = {0.f,0.f,0.f,0.f}, acc3 = {0.f,0.f,0.f,0.f};
    float ps = 0.f;

    __syncthreads();   // sjs + pwl visible before any STEP

    bf16x8 A0,A1,A2,A3, B0,B1,B2,B3, C0,C1,C2,C3, D0,D1,D2,D3;

#define LOADSET(S, jl)                                              \
    S##0 = *(const bf16x8*)(hrow + 0 * 16 * N + (jl));              \
    S##1 = *(const bf16x8*)(hrow + 1 * 16 * N + (jl));              \
    S##2 = *(const bf16x8*)(hrow + 2 * 16 * N + (jl));              \
    S##3 = *(const bf16x8*)(hrow + 3 * 16 * N + (jl));

#define STEP(S, jl)                                                 \
    {                                                               \
        const int jg = jbase + (jl);                                \
        const unsigned byte = (pwl[(jg >> 5) * 32 + lr] >> qc) & 0xffu; \
        const float4 s0 = *(const float4*)&sjs[jg + qc];            \
        const float4 s1 = *(const float4*)&sjs[jg + qc + 4];        \
        const float sv[8] = {s0.x,s0.y,s0.z,s0.w,s1.x,s1.y,s1.z,s1.w}; \
        bf16x8 af;                                                  \
        _Pragma("unroll")                                           \
        for (int e = 0; e < 8; ++e) {                               \
            const float ev0 = si + sv[e];                           \
            const float ev = fmaxf(ev0, NEG * ev0);                 \
            const float pe = ((byte >> e) & 1u) ? __expf(ev) : 0.f; \
            ps += pe;                                               \
            af[e] = f2bf(pe);                                       \
        }                                                           \
        acc0 = __builtin_amdgcn_mfma_f32_16x16x32_bf16(af, S##0, acc0, 0, 0, 0); \
        acc1 = __builtin_amdgcn_mfma_f32_16x16x32_bf16(af, S##1, acc1, 0, 0, 0); \
        acc2 = __builtin_amdgcn_mfma_f32_16x16x32_bf16(af, S##2, acc2, 0, 0, 0); \
        acc3 = __builtin_amdgcn_mfma_f32_16x16x32_bf16(af, S##3, acc3, 0, 0, 0); \
    }

    // prologue: 3 tiles in flight
    LOADSET(A, 0)
    LOADSET(B, 32)
    LOADSET(C, 64)

    // 16 iterations, 4-way rotation, all indices compile-time within each unrolled body
    for (int base = 0; base < 512; base += 128) {
        LOADSET(D, (base +  96) & 511)  STEP(A, base +  0)
        LOADSET(A, (base + 128) & 511)  STEP(B, base + 32)
        LOADSET(B, (base + 160) & 511)  STEP(C, base + 64)
        LOADSET(C, (base + 192) & 511)  STEP(D, base + 96)
    }
#undef LOADSET
#undef STEP

    // ---- Z partial: reduce over the 4 k-quarter lanes
    ps += __shfl_xor(ps, 16, 64);
    ps += __shfl_xor(ps, 32, 64);
    if (lane < 16) zbuf[w][lane] = ps;

    // ---- jh=1 waves dump accumulators to LDS
    if (w >= 2) {
        float* p = &accb[g][lane][0];
#pragma unroll
        for (int r = 0; r < 4; ++r) {
            p[r]      = acc0[r];
            p[4 + r]  = acc1[r];
            p[8 + r]  = acc2[r];
            p[12 + r] = acc3[r];
        }
    }
    __syncthreads();

    // ---- jh=0 waves combine + normalize + write
    if (w < 2) {
        const float* p = &accb[w][lane][0];
#pragma unroll
        for (int r = 0; r < 4; ++r) {
            acc0[r] += p[r];
            acc1[r] += p[4 + r];
            acc2[r] += p[8 + r];
            acc3[r] += p[12 + r];
        }
        float iz[4];
#pragma unroll
        for (int r = 0; r < 4; ++r)
            iz[r] = 1.f / (zbuf[w][q * 4 + r] + zbuf[w + 2][q * 4 + r]);

        float* __restrict__ ob = out + ((size_t)b * N + i0 + w * 16) * OUT_F + h * HD + il;
#pragma unroll
        for (int r = 0; r < 4; ++r) {
            float* o = ob + (size_t)(q * 4 + r) * OUT_F;
            o[0]  = acc0[r] * iz[r];
            o[16] = acc1[r] * iz[r];
            o[32] = acc2[r] * iz[r];
            o[48] = acc3[r] * iz[r];
        }
    }
}

extern "C" void kernel_launch(void* const* d_in, const int* in_sizes, int n_in,
                              void* d_out, int out_size, void* d_ws, size_t ws_size,
                              hipStream_t stream) {
    const float* x   = (const float*)d_in[0];
    const int*   adj = (const int*)d_in[1];
    const float* W   = (const float*)d_in[2];
    const float* a   = (const float*)d_in[3];
    float* out = (float*)d_out;

    unsigned short* hT = (unsigned short*)d_ws;                        // 4 MB bf16
    float* siT = (float*)(hT + (size_t)B * NH * HD * N);               // 128 KB
    float* sjT = siT + (size_t)B * NH * N;                             // 128 KB
    unsigned* pkdT = (unsigned*)(sjT + (size_t)B * NH * N);            // 1 MB

    k_pack<<<B * N, 256, 0, stream>>>(adj, pkdT);
    k_gemm<<<B * N / 8, 256, 0, stream>>>(x, W, a, hT, siT, sjT);
    k_pv<<<B * NH * (N / 32), 256, 0, stream>>>(hT, siT, sjT, pkdT, out);
}

// Round 9
// 47.931 us; speedup vs baseline: 1.9468x; 1.3307x over previous
//
#include <hip/hip_runtime.h>
#include <hip/hip_bf16.h>
#include <math.h>

constexpr int IN_F = 128, OUT_F = 256, NH = 4, HD = 64;
constexpr int B = 8, N = 1024;
#define NEG 0.2f

typedef __attribute__((ext_vector_type(8))) short bf16x8;
typedef __attribute__((ext_vector_type(4))) float f32x4;
typedef __attribute__((ext_vector_type(8))) unsigned short u16x8;

static __device__ __forceinline__ short f2bf(float f) {
    __hip_bfloat16 b = __float2bfloat16(f);
    return *reinterpret_cast<short*>(&b);
}

// ---------------- Kernel 0: bit-pack adjacency -> pkdT [B][16][32 w2][64 rows] ----------------
// grid = B*32 = 256 blocks (32-row chunk each), 256 threads. Coalesced reads AND writes;
// transpose via LDS so no cross-block 4B line sharing (R8 lesson: scattered 4B stores are slow).
__global__ __launch_bounds__(256) void k_pack(
    const int* __restrict__ adj,          // [B*N, N]
    unsigned* __restrict__ pkdT)
{
    __shared__ unsigned tr[32][33];       // [row][w2], padded
    const int bid = blockIdx.x;           // b*32 + ch
    const int b = bid >> 5, ch = bid & 31;
    const int t = threadIdx.x, lane = t & 63, w = t >> 6;
    const int n0 = ch * 32;               // row base within batch

    for (int rr = 0; rr < 8; ++rr) {
        const int rloc = w * 8 + rr;
        const int* __restrict__ src = adj + ((size_t)b * N + n0 + rloc) * N;
        unsigned myw = 0;
#pragma unroll
        for (int c = 0; c < 16; ++c) {
            const unsigned long long m = __ballot(src[c * 64 + lane] != 0); // bit l -> j=64c+l
            const unsigned lo = (unsigned)m, hi = (unsigned)(m >> 32);
            if ((lane >> 1) == c) myw = (lane & 1) ? hi : lo;   // lane 2c->lo, 2c+1->hi
        }
        if (lane < 32) tr[rloc][lane] = myw;
    }
    __syncthreads();

    // store 4 KB coalesced: thread t -> w2 = t>>3, rows r4..r4+3
    const int w2 = t >> 3, r4 = (t & 7) * 4;
    uint4 v;
    v.x = tr[r4 + 0][w2]; v.y = tr[r4 + 1][w2];
    v.z = tr[r4 + 2][w2]; v.w = tr[r4 + 3][w2];
    unsigned* __restrict__ dst = pkdT + ((size_t)(b * 16 + (ch >> 1))) * 32 * 64
                               + (size_t)w2 * 64 + (ch & 1) * 32 + r4;
    *(uint4*)dst = v;
}

// ---------------- Kernel 1: h = x @ W (round-2 proven version) ----------------
__global__ __launch_bounds__(256) void k_gemm(
    const float* __restrict__ x,          // [B*N, 128]
    const float* __restrict__ W,          // [128, 256]
    const float* __restrict__ a,          // [128]
    unsigned short* __restrict__ hT,      // [B][H][64][N] bf16 bits (transposed)
    float* __restrict__ siT,              // [B][H][N]
    float* __restrict__ sjT)              // [B][H][N]
{
    constexpr int ROWS = 8;
    __shared__ float xs[ROWS][IN_F];   // 4 KB
    const int t = threadIdx.x;
    const int row0 = blockIdx.x * ROWS;

    ((float4*)xs)[t] = ((const float4*)(x + (size_t)row0 * IN_F))[t];
    __syncthreads();

    float acc[ROWS];
#pragma unroll
    for (int r = 0; r < ROWS; ++r) acc[r] = 0.f;
    for (int k = 0; k < IN_F; ++k) {
        const float w = W[k * OUT_F + t];   // coalesced across t
#pragma unroll
        for (int r = 0; r < ROWS; ++r) acc[r] = fmaf(xs[r][k], w, acc[r]);
    }

    const int lane = t & 63, head = t >> 6, d = t & 63;
    const int b = row0 >> 10, n0 = row0 & (N - 1);

    u16x8 pk;
#pragma unroll
    for (int r = 0; r < ROWS; ++r) pk[r] = (unsigned short)f2bf(acc[r]);
    *(u16x8*)&hT[((size_t)(b * NH + head) * HD + d) * N + n0] = pk;

    const float ai = a[lane], aj = a[HD + lane];
#pragma unroll
    for (int r = 0; r < ROWS; ++r) {
        float si = acc[r] * ai;
        float sj = acc[r] * aj;
#pragma unroll
        for (int off = 32; off; off >>= 1) {
            si += __shfl_xor(si, off, 64);
            sj += __shfl_xor(sj, off, 64);
        }
        if (lane == 0) {
            siT[(size_t)(b * NH + head) * N + n0 + r] = si;
            sjT[(size_t)(b * NH + head) * N + n0 + r] = sj;
        }
    }
}

// ---------------- Kernel 2: MFMA PV; shared-LDS dbuf staging + LDS bitmask ----------------
// grid = B * H * (N/64) = 512 blocks, 256 threads (4 waves). Wave w: i-rows [i0+16w,+16), all j.
// Staging loads are contiguous (128B/row) and shared by all 4 waves -> minimal line-txns (R8 TA fix).
__global__ __launch_bounds__(256, 3) void k_pv(
    const unsigned short* __restrict__ hT,   // [B][H][64][N] bf16
    const float* __restrict__ siT,           // [B][H][N]
    const float* __restrict__ sjT,           // [B][H][N]
    const unsigned* __restrict__ pkdT,       // [B][16][32][64] packed bits
    float* __restrict__ out)                 // [B][N][256]
{
    constexpr int TJ = 64, NIT = N / TJ, PADJ = 72;   // 72: (il*9+q) mod 8 uniform -> no hot bank
    __shared__ __align__(16) short ht[2][64 * PADJ];  // 18 KB h-tile [d][j]
    __shared__ float sjs[N];                          // 4 KB
    __shared__ unsigned pwl[32 * 64];                 // 8 KB [w2][row]
    __shared__ float zbuf[4][16];

    const int bid = blockIdx.x;
    const int it = bid & 15, h = (bid >> 4) & 3, b = bid >> 6;
    const int t = threadIdx.x, lane = t & 63, w = t >> 6;
    const int i0 = it * 64;

    ((float4*)sjs)[t] = ((const float4*)(sjT + (size_t)(b * NH + h) * N))[t];
    {   // stage packed bits: 8 KB linear copy
        const uint4* ps = (const uint4*)(pkdT + ((size_t)(b * 16 + it)) * 32 * 64);
        ((uint4*)pwl)[t] = ps[t];
        ((uint4*)pwl)[t + 256] = ps[t + 256];
    }

    const int il = lane & 15, q = lane >> 4, qc = q * 8;
    const int lr = w * 16 + il;              // local i-row
    const float si = siT[(size_t)(b * NH + h) * N + i0 + lr];

    // staging: thread t owns h-row t>>2, col chunk (t&3)*16 (32 B contiguous)
    const int srow = t >> 2, sc = (t & 3) * 16;
    const unsigned short* __restrict__ hsrc =
        hT + (size_t)(b * NH + h) * HD * N + (size_t)srow * N + sc;
    short* const hd0 = &ht[0][srow * PADJ + sc];
    short* const hd1 = &ht[1][srow * PADJ + sc];

    f32x4 acc0 = {0.f,0.f,0.f,0.f}, acc1 = {0.f,0.f,0.f,0.f};
    f32x4 acc2 = {0.f,0.f,0.f,0.f}, acc3 = {0.f,0.f,0.f,0.f};
    float psA = 0.f, psB = 0.f;

    // preload tile 0 into regs
    u16x8 ra = *(const u16x8*)(hsrc);
    u16x8 rc = *(const u16x8*)(hsrc + 8);

    for (int itr = 0; itr < NIT; ++itr) {
        // write current tile to LDS (dbuf: one barrier per iter is race-free)
        short* const hd = (itr & 1) ? hd1 : hd0;
        *(u16x8*)hd = ra;
        *(u16x8*)(hd + 8) = rc;

        // prefetch next tile (wrap: harmless reload of tile 0 on last iter)
        const int jn = ((itr + 1) & (NIT - 1)) * TJ;
        ra = *(const u16x8*)(hsrc + jn);
        rc = *(const u16x8*)(hsrc + jn + 8);

        __syncthreads();
        const short* const hb = (itr & 1) ? ht[1] : ht[0];
        const int j0 = itr * TJ;

#define STEP(ks, PS)                                                         \
        {                                                                    \
            const unsigned byte = (pwl[(2 * itr + (ks)) * 64 + lr] >> qc) & 0xffu; \
            const int jq = j0 + (ks) * 32 + qc;                              \
            const float4 s0 = *(const float4*)&sjs[jq];                      \
            const float4 s1 = *(const float4*)&sjs[jq + 4];                  \
            const float sv[8] = {s0.x,s0.y,s0.z,s0.w,s1.x,s1.y,s1.z,s1.w};   \
            bf16x8 af;                                                       \
            _Pragma("unroll")                                                \
            for (int e = 0; e < 8; ++e) {                                    \
                const float ev0 = si + sv[e];                                \
                const float ev = fmaxf(ev0, NEG * ev0);                      \
                const float pe = ((byte >> e) & 1u) ? __expf(ev) : 0.f;      \
                PS += pe;                                                    \
                af[e] = f2bf(pe);                                            \
            }                                                                \
            const bf16x8 b0 = *(const bf16x8*)&hb[(0*16 + il)*PADJ + (ks)*32 + qc]; \
            const bf16x8 b1 = *(const bf16x8*)&hb[(1*16 + il)*PADJ + (ks)*32 + qc]; \
            const bf16x8 b2 = *(const bf16x8*)&hb[(2*16 + il)*PADJ + (ks)*32 + qc]; \
            const bf16x8 b3 = *(const bf16x8*)&hb[(3*16 + il)*PADJ + (ks)*32 + qc]; \
            acc0 = __builtin_amdgcn_mfma_f32_16x16x32_bf16(af, b0, acc0, 0, 0, 0); \
            acc1 = __builtin_amdgcn_mfma_f32_16x16x32_bf16(af, b1, acc1, 0, 0, 0); \
            acc2 = __builtin_amdgcn_mfma_f32_16x16x32_bf16(af, b2, acc2, 0, 0, 0); \
            acc3 = __builtin_amdgcn_mfma_f32_16x16x32_bf16(af, b3, acc3, 0, 0, 0); \
        }
        STEP(0, psA)
        STEP(1, psB)
#undef STEP
        __syncthreads();   // all waves done reading buf before it's overwritten next+1 iter
    }

    // ---- Z: reduce psum over the 4 k-quarter lanes of each row
    float ps = psA + psB;
    ps += __shfl_xor(ps, 16, 64);
    ps += __shfl_xor(ps, 32, 64);
    if (lane < 16) zbuf[w][lane] = ps;
    __syncthreads();

    // ---- epilogue: C/D layout col = lane&15, row = q*4 + reg
    float iz[4];
#pragma unroll
    for (int r = 0; r < 4; ++r) iz[r] = 1.f / zbuf[w][q * 4 + r];

    float* __restrict__ ob = out + ((size_t)b * N + i0 + w * 16) * OUT_F + h * HD + il;
#pragma unroll
    for (int r = 0; r < 4; ++r) {
        float* o = ob + (size_t)(q * 4 + r) * OUT_F;
        o[0]  = acc0[r] * iz[r];
        o[16] = acc1[r] * iz[r];
        o[32] = acc2[r] * iz[r];
        o[48] = acc3[r] * iz[r];
    }
}

extern "C" void kernel_launch(void* const* d_in, const int* in_sizes, int n_in,
                              void* d_out, int out_size, void* d_ws, size_t ws_size,
                              hipStream_t stream) {
    const float* x   = (const float*)d_in[0];
    const int*   adj = (const int*)d_in[1];
    const float* W   = (const float*)d_in[2];
    const float* a   = (const float*)d_in[3];
    float* out = (float*)d_out;

    unsigned short* hT = (unsigned short*)d_ws;                        // 4 MB bf16
    float* siT = (float*)(hT + (size_t)B * NH * HD * N);               // 128 KB
    float* sjT = siT + (size_t)B * NH * N;                             // 128 KB
    unsigned* pkdT = (unsigned*)(sjT + (size_t)B * NH * N);            // 1 MB

    k_pack<<<B * 32, 256, 0, stream>>>(adj, pkdT);
    k_gemm<<<B * N / 8, 256, 0, stream>>>(x, W, a, hT, siT, sjT);
    k_pv<<<B * NH * (N / 64), 256, 0, stream>>>(hT, siT, sjT, pkdT, out);
}